// Round 21
// baseline (143.532 us; speedup 1.0000x reference)
//
#include <hip/hip_runtime.h>

#define BATCH 16
#define SEQ   2048
#define EMB   1024
#define DH    128

typedef _Float16 half4_t __attribute__((ext_vector_type(4)));
typedef _Float16 half8_t __attribute__((ext_vector_type(8)));
typedef float    f32x4   __attribute__((ext_vector_type(4)));

// ---------------- workspace layout (bytes) ----------------
#define OFF_WT2 0u
#define OFF_QHI 0x200000u
#define OFF_QLO (OFF_QHI + 0x800000u)
#define OFF_KHI (OFF_QLO + 0x800000u)
#define OFF_KLO (OFF_KHI + 0x800000u)
#define OFF_VT  (OFF_KLO + 0x800000u)

// async global->LDS, 16B per lane (dst = wave-uniform base + lane*16)
__device__ __forceinline__ void gload16(const void* g, void* l) {
    __builtin_amdgcn_global_load_lds(
        (__attribute__((address_space(1))) const unsigned int*)g,
        (__attribute__((address_space(3))) unsigned int*)l, 16, 0, 0);
}

// ---------------- kernel 1: pack W into MFMA-fragment order ----------------
__global__ __launch_bounds__(256) void prep_w(
    const float* __restrict__ Wq, const float* __restrict__ Wk,
    const float* __restrict__ Wv, _Float16* __restrict__ Wt2) {
    const int t  = blockIdx.x * 256 + threadIdx.x;   // 0..81919
    const int kc = t / 2560, rem = t % 2560;
    const int lo = rem >= 1536 ? 1 : 0;
    const int rr = lo ? rem - 1536 : rem;
    const int nt = rr >> 6, c = rr & 63;             // c = g*16 + r
    const int g = c >> 4, r = c & 15;
    const int k0 = kc * 32 + g * 8;
    const float* W; int col;
    if (nt < 8)       { W = Wq; col = nt * 16 + r; }
    else if (nt < 16) { W = Wk; col = (nt - 8) * 16 + r; }
    else              { W = Wv; col = (nt - 16) * 16 + r; }
    half8_t v;
#pragma unroll
    for (int j = 0; j < 8; ++j) {
        float f = W[(size_t)(k0 + j) * DH + col];
        _Float16 h = (_Float16)f;
        v[j] = lo ? (_Float16)(f - (float)h) : h;
    }
    *(half8_t*)((char*)Wt2 + (size_t)kc * 40960 + (lo ? 24576 : 0)
                + (size_t)nt * 1024 + c * 16) = v;
}

// ---------------- kernel 2: QKV projection (all-LDS staging) ----------------
// BM=128, 8 waves, grid 256, BK=32, 32 phases. W staged to LDS alongside x
// (compute phase has zero VMEM). 80B frag row stride. (round-18/20 known-best)
#define XBUF  0        // 2 x 16KB fp32 x tiles (128 rows x 32 k)
#define WBUF  32768    // 2 x 40KB packed W chunk (hi 24KB + lo 16KB)
#define FHI   114688   // 10KB f16 hi frags [128 rows][4 slots][16B] stride 80
#define FLO   124928   // 10KB f16 lo frags

__global__ __launch_bounds__(512, 2) void proj_qkv(
    const float* __restrict__ x, const _Float16* __restrict__ Wt2,
    const float* __restrict__ bq, const float* __restrict__ bk,
    const float* __restrict__ bv,
    char* __restrict__ qhi, char* __restrict__ qlo,
    char* __restrict__ khi, char* __restrict__ klo,
    char* __restrict__ vt) {
    __shared__ __align__(16) char lds[135168];
    const int tid = threadIdx.x, lane = tid & 63, w = tid >> 6;  // w 0..7
    const int l15 = lane & 15, g = lane >> 4;
    const int m0  = blockIdx.x * 128;

    f32x4 acc[8][3];   // [mtile][q,k,v]
#pragma unroll
    for (int mt = 0; mt < 8; ++mt)
#pragma unroll
        for (int j = 0; j < 3; ++j) acc[mt][j] = {};

    // stage x phase t (128 rows x 32 k fp32 = 16KB); source-swizzled chunks
    auto stage_x = [&](int t, int buf) {
#pragma unroll
        for (int i = 0; i < 2; ++i) {
            const int cb = w * 128 + i * 64;         // wave-uniform slot base
            const int sidx = cb + lane;              // slot 0..1023
            const int r = sidx >> 3, s = sidx & 7;
            const int c = s ^ (r & 7);               // global chunk (involution)
            gload16(x + (size_t)(m0 + r) * EMB + t * 32 + c * 4,
                    lds + XBUF + buf * 16384 + cb * 16);
        }
    };

    // stage W chunk for kc=t (40KB, fully linear: pre-packed fragment order)
    auto stage_w = [&](int t, int buf) {
        const char* wsrc = (const char*)Wt2 + (size_t)t * 40960;
#pragma unroll
        for (int i = 0; i < 5; ++i) {
            const int off = (w * 5 + i) * 1024;
            gload16(wsrc + off + lane * 16, lds + WBUF + buf * 40960 + off);
        }
    };

    auto compute = [&](int buf) {
        const char* wb = lds + WBUF + buf * 40960;
        half8_t qh = *(const half8_t*)(wb + (size_t)w * 1024 + lane * 16);
        half8_t ql = *(const half8_t*)(wb + 24576 + (size_t)w * 1024 + lane * 16);
        half8_t kh = *(const half8_t*)(wb + (size_t)(8 + w) * 1024 + lane * 16);
        half8_t kl = *(const half8_t*)(wb + 24576 + (size_t)(8 + w) * 1024 + lane * 16);
        half8_t vh = *(const half8_t*)(wb + (size_t)(16 + w) * 1024 + lane * 16);
#pragma unroll
        for (int mt = 0; mt < 8; ++mt) {
            const int RR = mt * 16 + l15;
            const int sl = (g ^ ((RR >> 1) & 3)) * 16;   // 4-slot swizzle
            half8_t xh = *(const half8_t*)(lds + FHI + RR * 80 + sl);
            half8_t xl = *(const half8_t*)(lds + FLO + RR * 80 + sl);
            acc[mt][0] = __builtin_amdgcn_mfma_f32_16x16x32_f16(xh, qh, acc[mt][0], 0, 0, 0);
            acc[mt][0] = __builtin_amdgcn_mfma_f32_16x16x32_f16(xl, qh, acc[mt][0], 0, 0, 0);
            acc[mt][0] = __builtin_amdgcn_mfma_f32_16x16x32_f16(xh, ql, acc[mt][0], 0, 0, 0);
            acc[mt][1] = __builtin_amdgcn_mfma_f32_16x16x32_f16(xh, kh, acc[mt][1], 0, 0, 0);
            acc[mt][1] = __builtin_amdgcn_mfma_f32_16x16x32_f16(xl, kh, acc[mt][1], 0, 0, 0);
            acc[mt][1] = __builtin_amdgcn_mfma_f32_16x16x32_f16(xh, kl, acc[mt][1], 0, 0, 0);
            acc[mt][2] = __builtin_amdgcn_mfma_f32_16x16x32_f16(xh, vh, acc[mt][2], 0, 0, 0);
        }
    };

    stage_x(0, 0);
    stage_w(0, 0);

    for (int t = 0; t < 32; ++t) {
        __syncthreads();   // barA: x[t]+W[t] landed (staged last phase; vmcnt drained)

        // ---- cvt-exchange: 1 task/thread (128 rows x 4 slots = 512 tasks)
        {
            const char* Xb = lds + XBUF + (t & 1) * 16384;
            const int R = tid >> 2;                  // row 0..127
            const int s = tid & 3;                   // logical slot (k = s*8..s*8+7)
            const int rx = R & 7;
            f32x4 a0 = *(const f32x4*)(Xb + R * 128 + ((2 * s)     ^ rx) * 16);
            f32x4 a1 = *(const f32x4*)(Xb + R * 128 + ((2 * s + 1) ^ rx) * 16);
            half8_t hi, lo;
#pragma unroll
            for (int jj = 0; jj < 4; ++jj) {
                float f = a0[jj]; _Float16 h = (_Float16)f;
                hi[jj] = h; lo[jj] = (_Float16)(f - (float)h);
                float f2 = a1[jj]; _Float16 h2 = (_Float16)f2;
                hi[jj + 4] = h2; lo[jj + 4] = (_Float16)(f2 - (float)h2);
            }
            const int sw = (s ^ ((R >> 1) & 3)) * 16;
            *(half8_t*)(lds + FHI + R * 80 + sw) = hi;
            *(half8_t*)(lds + FLO + R * 80 + sw) = lo;
        }
        __syncthreads();   // barB: frags ready; buf[(t+1)&1] free

        if (t < 31) {      // prefetch next phase (in flight across compute)
            stage_x(t + 1, (t + 1) & 1);
            stage_w(t + 1, (t + 1) & 1);
        }
        __builtin_amdgcn_sched_barrier(0);

        compute(t & 1);    // zero VMEM instructions inside
    }

    // ---- epilogue: per-wave LDS 16x16 transpose -> packed coalesced stores ----
    __syncthreads();
    float* scr = (float*)(lds + (size_t)w * 1280);   // 16 rows x 20 f32 (padded)
    const float SC = 46.166241308446828f;            // 32*log2(e) folded into q

#pragma unroll
    for (int j = 0; j < 3; ++j) {
        float bias;
        if (j == 0)      bias = bq[w * 16 + l15];
        else if (j == 1) bias = bk[w * 16 + l15];
        else             bias = bv[w * 16 + l15];
#pragma unroll
        for (int mt = 0; mt < 8; ++mt) {
            f32x4 a = acc[mt][j];
#pragma unroll
            for (int r = 0; r < 4; ++r) {
                float v = a[r] + bias;
                if (j == 0) v *= SC;
                scr[(g * 4 + r) * 20 + l15] = v;     // [tok][dh]
            }
            if (j < 2) {                             // ---- q,k: frag-packed store
                f32x4 tv = *(const f32x4*)(scr + l15 * 20 + g * 4);
                half4_t h4, l4;
#pragma unroll
                for (int r = 0; r < 4; ++r) {
                    _Float16 h = (_Float16)tv[r];
                    h4[r] = h; l4[r] = (_Float16)(tv[r] - (float)h);
                }
                const int tIdx = blockIdx.x * 8 + mt;
                const int octm = 2 * w + (g >> 1);   // 0..15 for both q and k
                const size_t off = (size_t)tIdx * 4096 + (octm >> 2) * 1024
                                 + (octm & 3) * 256 + l15 * 16 + (g & 1) * 8;
                char* dh_ = (j == 0) ? qhi : khi;
                char* dl_ = (j == 0) ? qlo : klo;
                *(half4_t*)(dh_ + off) = h4;
                *(half4_t*)(dl_ + off) = l4;
            } else {                                 // ---- v: packed store
                half4_t v4;
#pragma unroll
                for (int r = 0; r < 4; ++r)
                    v4[r] = (_Float16)scr[(g * 4 + r) * 20 + l15];
                const int s0 = (m0 & (SEQ - 1)) + mt * 16;
                const int b  = m0 >> 11;
                const size_t off = ((size_t)b * 64 + (s0 >> 5)) * 8192
                                 + ((s0 >> 4) & 1) * 4096 + (size_t)w * 512
                                 + g * 128 + l15 * 8;
                *(half4_t*)(vt + off) = v4;
            }
        }
    }
}

// ---------------- kernel 3: fused-pair causal flash attention ----------------
// 256 blocks x 8 waves. Waves 0-3: jt=31-pr; waves 4-7: jt=pr. Shared KV
// staging stream; setprio around MFMA clusters; deferred ell reduction.
// QK lo-path split into TWO accumulators (4-deep chains instead of 8-deep)
// to relieve MFMA dependency latency at 2 waves/SIMD.
__global__ __launch_bounds__(512) void attn(
    const char* __restrict__ qhi, const char* __restrict__ qlo,
    const char* __restrict__ khi, const char* __restrict__ klo,
    const char* __restrict__ vt, float* __restrict__ out) {
    __shared__ __align__(16) char lds[49152];
    const int tid = threadIdx.x, lane = tid & 63, w = tid >> 6;  // w 0..7
    const int l15 = lane & 15, g = lane >> 4;
    const int gid = blockIdx.x;
    const int b   = ((gid & 7) << 1) | ((gid >> 3) & 1);  // 2 batches per XCD
    const int pr  = gid >> 4;                              // pair index 0..15
    const int jt  = (w < 4) ? (31 - pr) : pr;              // big tile on waves 0-3
    const int wq  = w & 3;
    const int qw0 = jt * 64 + wq * 16;
    const int nkv = 2 * (32 - pr);                         // max over the pair

    auto stage = [&](int t, int buf) {
        char* dst = lds + buf * 24576;
        const size_t kb4 = ((size_t)b * 128 + t * 2) * 4096;
        const size_t vb8 = ((size_t)b * 64 + t) * 8192;
        const int off = w * 1024;                          // 8 waves x 1KB each
        gload16(khi + kb4 + off + lane * 16, dst + off);
        gload16(klo + kb4 + off + lane * 16, dst + 8192 + off);
        gload16(vt  + vb8 + off + lane * 16, dst + 16384 + off);
    };

    const size_t qt4 = ((size_t)b * 128 + (qw0 >> 4)) * 4096;
    half8_t Qh[4], Ql[4];
#pragma unroll
    for (int kk = 0; kk < 4; ++kk) {
        const size_t o = qt4 + kk * 1024 + g * 256 + l15 * 16;
        Qh[kk] = *(const half8_t*)(qhi + o);
        Ql[kk] = *(const half8_t*)(qlo + o);
    }

    f32x4 o[8];
#pragma unroll
    for (int dt = 0; dt < 8; ++dt) o[dt] = {};
    float mrun = -3.0e38f, ell = 0.0f;   // ell: PER-LANE partial (reduced at end)

    stage(0, 0);

    for (int t = 0; t < nkv; ++t) {
        __syncthreads();                       // buf[t&1] staged (vmcnt drained)
        if (t + 1 < nkv) stage(t + 1, (t + 1) & 1);

        const int kb = t * 32;
        if (kb <= qw0 + 15) {                  // wave-uniform skip
            const char* kbuf = lds + (t & 1) * 24576;

            // 6 accumulators: sa (hi*hi) + sbx (lo*hi) + sby (hi*lo), per half
            f32x4 sa0 = {}, sbx0 = {}, sby0 = {};
            f32x4 sa1 = {}, sbx1 = {}, sby1 = {};
            __builtin_amdgcn_s_setprio(1);
#pragma unroll
            for (int kk = 0; kk < 4; ++kk) {
                const int fo = kk * 1024 + g * 256 + l15 * 16;
                half8_t kh0 = *(const half8_t*)(kbuf + fo);
                half8_t kl0 = *(const half8_t*)(kbuf + 8192 + fo);
                half8_t kh1 = *(const half8_t*)(kbuf + 4096 + fo);
                half8_t kl1 = *(const half8_t*)(kbuf + 12288 + fo);
                sa0  = __builtin_amdgcn_mfma_f32_16x16x32_f16(kh0, Qh[kk], sa0,  0, 0, 0);
                sbx0 = __builtin_amdgcn_mfma_f32_16x16x32_f16(kl0, Qh[kk], sbx0, 0, 0, 0);
                sby0 = __builtin_amdgcn_mfma_f32_16x16x32_f16(kh0, Ql[kk], sby0, 0, 0, 0);
                sa1  = __builtin_amdgcn_mfma_f32_16x16x32_f16(kh1, Qh[kk], sa1,  0, 0, 0);
                sbx1 = __builtin_amdgcn_mfma_f32_16x16x32_f16(kl1, Qh[kk], sbx1, 0, 0, 0);
                sby1 = __builtin_amdgcn_mfma_f32_16x16x32_f16(kh1, Ql[kk], sby1, 0, 0, 0);
            }
            __builtin_amdgcn_s_setprio(0);
            f32x4 s0 = sa0 + (sbx0 + sby0), s1 = sa1 + (sbx1 + sby1);

            if (kb + 31 > qw0) {               // diagonal region: causal mask
#pragma unroll
                for (int r = 0; r < 4; ++r) {
                    if (kb + g * 4 + r      > qw0 + l15) s0[r] = -3.0e38f;
                    if (kb + 16 + g * 4 + r > qw0 + l15) s1[r] = -3.0e38f;
                }
            }

            float mt = fmaxf(fmaxf(fmaxf(s0[0], s0[1]), fmaxf(s0[2], s0[3])),
                             fmaxf(fmaxf(s1[0], s1[1]), fmaxf(s1[2], s1[3])));
            mt = fmaxf(mt, __shfl_xor(mt, 16, 64));
            mt = fmaxf(mt, __shfl_xor(mt, 32, 64));
            if (!__all(mt <= mrun + 8.0f)) {   // defer-max (log2 units)
                const float mnew = fmaxf(mrun, mt);
                const float alpha = exp2f(mrun - mnew);   // uniform per q-column
                ell *= alpha;
#pragma unroll
                for (int dt = 0; dt < 8; ++dt) o[dt] *= alpha;
                mrun = mnew;
            }
            float p[8];
#pragma unroll
            for (int r = 0; r < 4; ++r) {
                p[r]     = exp2f(s0[r] - mrun);
                p[4 + r] = exp2f(s1[r] - mrun);
            }
            ell += ((p[0] + p[1]) + (p[2] + p[3])) + ((p[4] + p[5]) + (p[6] + p[7]));

            half4_t pf0, pf1;
#pragma unroll
            for (int r = 0; r < 4; ++r) { pf0[r] = (_Float16)p[r]; pf1[r] = (_Float16)p[4 + r]; }

            const char* vbuf = kbuf + 16384;
            __builtin_amdgcn_s_setprio(1);
#pragma unroll
            for (int dt = 0; dt < 8; ++dt) {
                const int vo = dt * 512 + g * 128 + l15 * 8;
                half4_t v0 = *(const half4_t*)(vbuf + vo);
                half4_t v1 = *(const half4_t*)(vbuf + 4096 + vo);
                o[dt] = __builtin_amdgcn_mfma_f32_16x16x16f16(v0, pf0, o[dt], 0, 0, 0);
                o[dt] = __builtin_amdgcn_mfma_f32_16x16x16f16(v1, pf1, o[dt], 0, 0, 0);
            }
            __builtin_amdgcn_s_setprio(0);
        }
    }

    ell += __shfl_xor(ell, 16, 64);
    ell += __shfl_xor(ell, 32, 64);

    const float rinv = 1.0f / ell;
    float* orow = out + ((size_t)b * SEQ + qw0 + l15) * DH + g * 4;
#pragma unroll
    for (int dt = 0; dt < 8; ++dt) {
        f32x4 ov = o[dt] * rinv;
        *(f32x4*)(orow + dt * 16) = ov;
    }
}

extern "C" void kernel_launch(void* const* d_in, const int* in_sizes, int n_in,
                              void* d_out, int out_size, void* d_ws, size_t ws_size,
                              hipStream_t stream) {
    const float* x  = (const float*)d_in[0];
    const float* Wq = (const float*)d_in[1];
    const float* bq = (const float*)d_in[2];
    const float* Wk = (const float*)d_in[3];
    const float* bk = (const float*)d_in[4];
    const float* Wv = (const float*)d_in[5];
    const float* bv = (const float*)d_in[6];
    float* out = (float*)d_out;

    char* ws = (char*)d_ws;
    _Float16* Wt2 = (_Float16*)(ws + OFF_WT2);
    char* q_hi = ws + OFF_QHI;
    char* q_lo = ws + OFF_QLO;
    char* k_hi = ws + OFF_KHI;
    char* k_lo = ws + OFF_KLO;
    char* v_t  = ws + OFF_VT;

    prep_w  <<<320, 256, 0, stream>>>(Wq, Wk, Wv, Wt2);
    proj_qkv<<<256, 512, 0, stream>>>(x, Wt2, bq, bk, bv, q_hi, q_lo, k_hi, k_lo, v_t);
    attn    <<<256, 512, 0, stream>>>(q_hi, q_lo, k_hi, k_lo, v_t, out);
}

// Round 22
// 139.139 us; speedup vs baseline: 1.0316x; 1.0316x over previous
//
#include <hip/hip_runtime.h>

#define BATCH 16
#define SEQ   2048
#define EMB   1024
#define DH    128

typedef _Float16 half4_t __attribute__((ext_vector_type(4)));
typedef _Float16 half8_t __attribute__((ext_vector_type(8)));
typedef float    f32x4   __attribute__((ext_vector_type(4)));

// ---------------- workspace layout (bytes) ----------------
#define OFF_WT2 0u
#define OFF_QHI 0x200000u
#define OFF_QLO (OFF_QHI + 0x800000u)
#define OFF_KHI (OFF_QLO + 0x800000u)
#define OFF_KLO (OFF_KHI + 0x800000u)
#define OFF_VT  (OFF_KLO + 0x800000u)

// async global->LDS, 16B per lane (dst = wave-uniform base + lane*16)
__device__ __forceinline__ void gload16(const void* g, void* l) {
    __builtin_amdgcn_global_load_lds(
        (__attribute__((address_space(1))) const unsigned int*)g,
        (__attribute__((address_space(3))) unsigned int*)l, 16, 0, 0);
}

// ---------------- kernel 1: pack W into MFMA-fragment order ----------------
__global__ __launch_bounds__(256) void prep_w(
    const float* __restrict__ Wq, const float* __restrict__ Wk,
    const float* __restrict__ Wv, _Float16* __restrict__ Wt2) {
    const int t  = blockIdx.x * 256 + threadIdx.x;   // 0..81919
    const int kc = t / 2560, rem = t % 2560;
    const int lo = rem >= 1536 ? 1 : 0;
    const int rr = lo ? rem - 1536 : rem;
    const int nt = rr >> 6, c = rr & 63;             // c = g*16 + r
    const int g = c >> 4, r = c & 15;
    const int k0 = kc * 32 + g * 8;
    const float* W; int col;
    if (nt < 8)       { W = Wq; col = nt * 16 + r; }
    else if (nt < 16) { W = Wk; col = (nt - 8) * 16 + r; }
    else              { W = Wv; col = (nt - 16) * 16 + r; }
    half8_t v;
#pragma unroll
    for (int j = 0; j < 8; ++j) {
        float f = W[(size_t)(k0 + j) * DH + col];
        _Float16 h = (_Float16)f;
        v[j] = lo ? (_Float16)(f - (float)h) : h;
    }
    *(half8_t*)((char*)Wt2 + (size_t)kc * 40960 + (lo ? 24576 : 0)
                + (size_t)nt * 1024 + c * 16) = v;
}

// ---------------- kernel 2: QKV projection (all-LDS staging) ----------------
// BM=128, 8 waves, grid 256, BK=32, 32 phases. W staged to LDS alongside x
// (compute phase has zero VMEM). 80B frag row stride. (round-18/20 known-best)
#define XBUF  0        // 2 x 16KB fp32 x tiles (128 rows x 32 k)
#define WBUF  32768    // 2 x 40KB packed W chunk (hi 24KB + lo 16KB)
#define FHI   114688   // 10KB f16 hi frags [128 rows][4 slots][16B] stride 80
#define FLO   124928   // 10KB f16 lo frags

__global__ __launch_bounds__(512, 2) void proj_qkv(
    const float* __restrict__ x, const _Float16* __restrict__ Wt2,
    const float* __restrict__ bq, const float* __restrict__ bk,
    const float* __restrict__ bv,
    char* __restrict__ qhi, char* __restrict__ qlo,
    char* __restrict__ khi, char* __restrict__ klo,
    char* __restrict__ vt) {
    __shared__ __align__(16) char lds[135168];
    const int tid = threadIdx.x, lane = tid & 63, w = tid >> 6;  // w 0..7
    const int l15 = lane & 15, g = lane >> 4;
    const int m0  = blockIdx.x * 128;

    f32x4 acc[8][3];   // [mtile][q,k,v]
#pragma unroll
    for (int mt = 0; mt < 8; ++mt)
#pragma unroll
        for (int j = 0; j < 3; ++j) acc[mt][j] = {};

    // stage x phase t (128 rows x 32 k fp32 = 16KB); source-swizzled chunks
    auto stage_x = [&](int t, int buf) {
#pragma unroll
        for (int i = 0; i < 2; ++i) {
            const int cb = w * 128 + i * 64;         // wave-uniform slot base
            const int sidx = cb + lane;              // slot 0..1023
            const int r = sidx >> 3, s = sidx & 7;
            const int c = s ^ (r & 7);               // global chunk (involution)
            gload16(x + (size_t)(m0 + r) * EMB + t * 32 + c * 4,
                    lds + XBUF + buf * 16384 + cb * 16);
        }
    };

    // stage W chunk for kc=t (40KB, fully linear: pre-packed fragment order)
    auto stage_w = [&](int t, int buf) {
        const char* wsrc = (const char*)Wt2 + (size_t)t * 40960;
#pragma unroll
        for (int i = 0; i < 5; ++i) {
            const int off = (w * 5 + i) * 1024;
            gload16(wsrc + off + lane * 16, lds + WBUF + buf * 40960 + off);
        }
    };

    auto compute = [&](int buf) {
        const char* wb = lds + WBUF + buf * 40960;
        half8_t qh = *(const half8_t*)(wb + (size_t)w * 1024 + lane * 16);
        half8_t ql = *(const half8_t*)(wb + 24576 + (size_t)w * 1024 + lane * 16);
        half8_t kh = *(const half8_t*)(wb + (size_t)(8 + w) * 1024 + lane * 16);
        half8_t kl = *(const half8_t*)(wb + 24576 + (size_t)(8 + w) * 1024 + lane * 16);
        half8_t vh = *(const half8_t*)(wb + (size_t)(16 + w) * 1024 + lane * 16);
#pragma unroll
        for (int mt = 0; mt < 8; ++mt) {
            const int RR = mt * 16 + l15;
            const int sl = (g ^ ((RR >> 1) & 3)) * 16;   // 4-slot swizzle
            half8_t xh = *(const half8_t*)(lds + FHI + RR * 80 + sl);
            half8_t xl = *(const half8_t*)(lds + FLO + RR * 80 + sl);
            acc[mt][0] = __builtin_amdgcn_mfma_f32_16x16x32_f16(xh, qh, acc[mt][0], 0, 0, 0);
            acc[mt][0] = __builtin_amdgcn_mfma_f32_16x16x32_f16(xl, qh, acc[mt][0], 0, 0, 0);
            acc[mt][0] = __builtin_amdgcn_mfma_f32_16x16x32_f16(xh, ql, acc[mt][0], 0, 0, 0);
            acc[mt][1] = __builtin_amdgcn_mfma_f32_16x16x32_f16(xh, kh, acc[mt][1], 0, 0, 0);
            acc[mt][1] = __builtin_amdgcn_mfma_f32_16x16x32_f16(xl, kh, acc[mt][1], 0, 0, 0);
            acc[mt][1] = __builtin_amdgcn_mfma_f32_16x16x32_f16(xh, kl, acc[mt][1], 0, 0, 0);
            acc[mt][2] = __builtin_amdgcn_mfma_f32_16x16x32_f16(xh, vh, acc[mt][2], 0, 0, 0);
        }
    };

    stage_x(0, 0);
    stage_w(0, 0);

    for (int t = 0; t < 32; ++t) {
        __syncthreads();   // barA: x[t]+W[t] landed (staged last phase; vmcnt drained)

        // ---- cvt-exchange: 1 task/thread (128 rows x 4 slots = 512 tasks)
        {
            const char* Xb = lds + XBUF + (t & 1) * 16384;
            const int R = tid >> 2;                  // row 0..127
            const int s = tid & 3;                   // logical slot (k = s*8..s*8+7)
            const int rx = R & 7;
            f32x4 a0 = *(const f32x4*)(Xb + R * 128 + ((2 * s)     ^ rx) * 16);
            f32x4 a1 = *(const f32x4*)(Xb + R * 128 + ((2 * s + 1) ^ rx) * 16);
            half8_t hi, lo;
#pragma unroll
            for (int jj = 0; jj < 4; ++jj) {
                float f = a0[jj]; _Float16 h = (_Float16)f;
                hi[jj] = h; lo[jj] = (_Float16)(f - (float)h);
                float f2 = a1[jj]; _Float16 h2 = (_Float16)f2;
                hi[jj + 4] = h2; lo[jj + 4] = (_Float16)(f2 - (float)h2);
            }
            const int sw = (s ^ ((R >> 1) & 3)) * 16;
            *(half8_t*)(lds + FHI + R * 80 + sw) = hi;
            *(half8_t*)(lds + FLO + R * 80 + sw) = lo;
        }
        __syncthreads();   // barB: frags ready; buf[(t+1)&1] free

        if (t < 31) {      // prefetch next phase (in flight across compute)
            stage_x(t + 1, (t + 1) & 1);
            stage_w(t + 1, (t + 1) & 1);
        }
        __builtin_amdgcn_sched_barrier(0);

        compute(t & 1);    // zero VMEM instructions inside
    }

    // ---- epilogue: per-wave LDS 16x16 transpose -> packed coalesced stores ----
    __syncthreads();
    float* scr = (float*)(lds + (size_t)w * 1280);   // 16 rows x 20 f32 (padded)
    const float SC = 46.166241308446828f;            // 32*log2(e) folded into q

#pragma unroll
    for (int j = 0; j < 3; ++j) {
        float bias;
        if (j == 0)      bias = bq[w * 16 + l15];
        else if (j == 1) bias = bk[w * 16 + l15];
        else             bias = bv[w * 16 + l15];
#pragma unroll
        for (int mt = 0; mt < 8; ++mt) {
            f32x4 a = acc[mt][j];
#pragma unroll
            for (int r = 0; r < 4; ++r) {
                float v = a[r] + bias;
                if (j == 0) v *= SC;
                scr[(g * 4 + r) * 20 + l15] = v;     // [tok][dh]
            }
            if (j < 2) {                             // ---- q,k: frag-packed store
                f32x4 tv = *(const f32x4*)(scr + l15 * 20 + g * 4);
                half4_t h4, l4;
#pragma unroll
                for (int r = 0; r < 4; ++r) {
                    _Float16 h = (_Float16)tv[r];
                    h4[r] = h; l4[r] = (_Float16)(tv[r] - (float)h);
                }
                const int tIdx = blockIdx.x * 8 + mt;
                const int octm = 2 * w + (g >> 1);   // 0..15 for both q and k
                const size_t off = (size_t)tIdx * 4096 + (octm >> 2) * 1024
                                 + (octm & 3) * 256 + l15 * 16 + (g & 1) * 8;
                char* dh_ = (j == 0) ? qhi : khi;
                char* dl_ = (j == 0) ? qlo : klo;
                *(half4_t*)(dh_ + off) = h4;
                *(half4_t*)(dl_ + off) = l4;
            } else {                                 // ---- v: packed store
                half4_t v4;
#pragma unroll
                for (int r = 0; r < 4; ++r)
                    v4[r] = (_Float16)scr[(g * 4 + r) * 20 + l15];
                const int s0 = (m0 & (SEQ - 1)) + mt * 16;
                const int b  = m0 >> 11;
                const size_t off = ((size_t)b * 64 + (s0 >> 5)) * 8192
                                 + ((s0 >> 4) & 1) * 4096 + (size_t)w * 512
                                 + g * 128 + l15 * 8;
                *(half4_t*)(vt + off) = v4;
            }
        }
    }
}

// ---------------- kernel 3: fused-pair causal flash attention ----------------
// 256 blocks x 8 waves. Waves 0-3: jt=31-pr; waves 4-7: jt=pr. Shared KV
// staging stream; setprio around MFMA clusters; deferred ell reduction.
__global__ __launch_bounds__(512) void attn(
    const char* __restrict__ qhi, const char* __restrict__ qlo,
    const char* __restrict__ khi, const char* __restrict__ klo,
    const char* __restrict__ vt, float* __restrict__ out) {
    __shared__ __align__(16) char lds[49152];
    const int tid = threadIdx.x, lane = tid & 63, w = tid >> 6;  // w 0..7
    const int l15 = lane & 15, g = lane >> 4;
    const int gid = blockIdx.x;
    const int b   = ((gid & 7) << 1) | ((gid >> 3) & 1);  // 2 batches per XCD
    const int pr  = gid >> 4;                              // pair index 0..15
    const int jt  = (w < 4) ? (31 - pr) : pr;              // big tile on waves 0-3
    const int wq  = w & 3;
    const int qw0 = jt * 64 + wq * 16;
    const int nkv = 2 * (32 - pr);                         // max over the pair

    auto stage = [&](int t, int buf) {
        char* dst = lds + buf * 24576;
        const size_t kb4 = ((size_t)b * 128 + t * 2) * 4096;
        const size_t vb8 = ((size_t)b * 64 + t) * 8192;
        const int off = w * 1024;                          // 8 waves x 1KB each
        gload16(khi + kb4 + off + lane * 16, dst + off);
        gload16(klo + kb4 + off + lane * 16, dst + 8192 + off);
        gload16(vt  + vb8 + off + lane * 16, dst + 16384 + off);
    };

    const size_t qt4 = ((size_t)b * 128 + (qw0 >> 4)) * 4096;
    half8_t Qh[4], Ql[4];
#pragma unroll
    for (int kk = 0; kk < 4; ++kk) {
        const size_t o = qt4 + kk * 1024 + g * 256 + l15 * 16;
        Qh[kk] = *(const half8_t*)(qhi + o);
        Ql[kk] = *(const half8_t*)(qlo + o);
    }

    f32x4 o[8];
#pragma unroll
    for (int dt = 0; dt < 8; ++dt) o[dt] = {};
    float mrun = -3.0e38f, ell = 0.0f;   // ell: PER-LANE partial (reduced at end)

    stage(0, 0);

    for (int t = 0; t < nkv; ++t) {
        __syncthreads();                       // buf[t&1] staged (vmcnt drained)
        if (t + 1 < nkv) stage(t + 1, (t + 1) & 1);

        const int kb = t * 32;
        if (kb <= qw0 + 15) {                  // wave-uniform skip
            const char* kbuf = lds + (t & 1) * 24576;

            f32x4 sa0 = {}, sb0 = {}, sa1 = {}, sb1 = {};
            __builtin_amdgcn_s_setprio(1);
#pragma unroll
            for (int kk = 0; kk < 4; ++kk) {
                const int fo = kk * 1024 + g * 256 + l15 * 16;
                half8_t kh0 = *(const half8_t*)(kbuf + fo);
                half8_t kl0 = *(const half8_t*)(kbuf + 8192 + fo);
                half8_t kh1 = *(const half8_t*)(kbuf + 4096 + fo);
                half8_t kl1 = *(const half8_t*)(kbuf + 12288 + fo);
                sa0 = __builtin_amdgcn_mfma_f32_16x16x32_f16(kh0, Qh[kk], sa0, 0, 0, 0);
                sb0 = __builtin_amdgcn_mfma_f32_16x16x32_f16(kl0, Qh[kk], sb0, 0, 0, 0);
                sb0 = __builtin_amdgcn_mfma_f32_16x16x32_f16(kh0, Ql[kk], sb0, 0, 0, 0);
                sa1 = __builtin_amdgcn_mfma_f32_16x16x32_f16(kh1, Qh[kk], sa1, 0, 0, 0);
                sb1 = __builtin_amdgcn_mfma_f32_16x16x32_f16(kl1, Qh[kk], sb1, 0, 0, 0);
                sb1 = __builtin_amdgcn_mfma_f32_16x16x32_f16(kh1, Ql[kk], sb1, 0, 0, 0);
            }
            __builtin_amdgcn_s_setprio(0);
            f32x4 s0 = sa0 + sb0, s1 = sa1 + sb1;

            if (kb + 31 > qw0) {               // diagonal region: causal mask
#pragma unroll
                for (int r = 0; r < 4; ++r) {
                    if (kb + g * 4 + r      > qw0 + l15) s0[r] = -3.0e38f;
                    if (kb + 16 + g * 4 + r > qw0 + l15) s1[r] = -3.0e38f;
                }
            }

            float mt = fmaxf(fmaxf(fmaxf(s0[0], s0[1]), fmaxf(s0[2], s0[3])),
                             fmaxf(fmaxf(s1[0], s1[1]), fmaxf(s1[2], s1[3])));
            mt = fmaxf(mt, __shfl_xor(mt, 16, 64));
            mt = fmaxf(mt, __shfl_xor(mt, 32, 64));
            if (!__all(mt <= mrun + 8.0f)) {   // defer-max (log2 units)
                const float mnew = fmaxf(mrun, mt);
                const float alpha = exp2f(mrun - mnew);   // uniform per q-column
                ell *= alpha;
#pragma unroll
                for (int dt = 0; dt < 8; ++dt) o[dt] *= alpha;
                mrun = mnew;
            }
            float p[8];
#pragma unroll
            for (int r = 0; r < 4; ++r) {
                p[r]     = exp2f(s0[r] - mrun);
                p[4 + r] = exp2f(s1[r] - mrun);
            }
            ell += ((p[0] + p[1]) + (p[2] + p[3])) + ((p[4] + p[5]) + (p[6] + p[7]));

            half4_t pf0, pf1;
#pragma unroll
            for (int r = 0; r < 4; ++r) { pf0[r] = (_Float16)p[r]; pf1[r] = (_Float16)p[4 + r]; }

            const char* vbuf = kbuf + 16384;
            __builtin_amdgcn_s_setprio(1);
#pragma unroll
            for (int dt = 0; dt < 8; ++dt) {
                const int vo = dt * 512 + g * 128 + l15 * 8;
                half4_t v0 = *(const half4_t*)(vbuf + vo);
                half4_t v1 = *(const half4_t*)(vbuf + 4096 + vo);
                o[dt] = __builtin_amdgcn_mfma_f32_16x16x16f16(v0, pf0, o[dt], 0, 0, 0);
                o[dt] = __builtin_amdgcn_mfma_f32_16x16x16f16(v1, pf1, o[dt], 0, 0, 0);
            }
            __builtin_amdgcn_s_setprio(0);
        }
    }

    ell += __shfl_xor(ell, 16, 64);
    ell += __shfl_xor(ell, 32, 64);

    const float rinv = 1.0f / ell;
    float* orow = out + ((size_t)b * SEQ + qw0 + l15) * DH + g * 4;
#pragma unroll
    for (int dt = 0; dt < 8; ++dt) {
        f32x4 ov = o[dt] * rinv;
        *(f32x4*)(orow + dt * 16) = ov;
    }
}

extern "C" void kernel_launch(void* const* d_in, const int* in_sizes, int n_in,
                              void* d_out, int out_size, void* d_ws, size_t ws_size,
                              hipStream_t stream) {
    const float* x  = (const float*)d_in[0];
    const float* Wq = (const float*)d_in[1];
    const float* bq = (const float*)d_in[2];
    const float* Wk = (const float*)d_in[3];
    const float* bk = (const float*)d_in[4];
    const float* Wv = (const float*)d_in[5];
    const float* bv = (const float*)d_in[6];
    float* out = (float*)d_out;

    char* ws = (char*)d_ws;
    _Float16* Wt2 = (_Float16*)(ws + OFF_WT2);
    char* q_hi = ws + OFF_QHI;
    char* q_lo = ws + OFF_QLO;
    char* k_hi = ws + OFF_KHI;
    char* k_lo = ws + OFF_KLO;
    char* v_t  = ws + OFF_VT;

    prep_w  <<<320, 256, 0, stream>>>(Wq, Wk, Wv, Wt2);
    proj_qkv<<<256, 512, 0, stream>>>(x, Wt2, bq, bk, bv, q_hi, q_lo, k_hi, k_lo, v_t);
    attn    <<<256, 512, 0, stream>>>(q_hi, q_lo, k_hi, k_lo, v_t, out);
}